// Round 1
// 282.750 us; speedup vs baseline: 1.0465x; 1.0465x over previous
//
#include <hip/hip_runtime.h>
#include <hip/hip_bf16.h>
#include <math.h>

#define NB 8
#define CC 512
#define HH 64
#define WW 64
#define GG 16
#define GCH 32
#define OO 32                      // 2*G offset rows
#define NGHW (NB * GG * HH * WW)   // 524288 elements per coord buffer
#define NPX  (NB * HH * WW)        // 32768 pixels
#define XROW 520                   // LDS x1 row stride in bf16 (1040 B: 16B-aligned, odd multiple of 16B -> conflict-free MFMA reads)

// ws layout: [0, 4 MiB) px/py coords. (x1 never touches HBM anymore.)

__device__ __forceinline__ float gelu_exact(float x) {
    return 0.5f * x * (1.0f + erff(x * 0.70710678118654752f));
}

__device__ __forceinline__ unsigned pack_bf2(float a, float b) {
    __hip_bfloat162 t = __float22bfloat162_rn(make_float2(a, b));
    return *(unsigned*)&t;
}

typedef __attribute__((ext_vector_type(8))) short bf16x8;
typedef __attribute__((ext_vector_type(4))) float f32x4;

// ============================================================================
// Fused kernel: dwconv3x3 + LayerNorm + GELU + offset-GEMM -> coords.
// grid (HH, NB), block 1024; conv thread = 2 w x 16 ch (float2 loads + shfl
// halo). Persistent fp32 accumulator is 32 VGPRs (was 64) so the compiler can
// keep several row-loads in flight -> attack the 75% latency stall seen in
// rocprof (VALUBusy 26%, occupancy 21%). x1 (bf16) goes to LDS only; waves
// 0-7 then run the verified 16x16 MFMA tile (K=512) from kernel 2 and emit
// coords directly. Numerics identical to the previous passing version: conv
// and LN stats exact fp32; x1 quantized to bf16 at the same point.
// ============================================================================
__global__ __launch_bounds__(1024, 4)
void fused_conv_ln_gelu_off_kernel(const float* __restrict__ in_first,
                                   const float* __restrict__ dw_w,
                                   const float* __restrict__ dw_b,
                                   const float* __restrict__ ln_g,
                                   const float* __restrict__ ln_b,
                                   const float* __restrict__ off_w,
                                   const float* __restrict__ off_b,
                                   float* __restrict__ coords)
{
    const int h    = blockIdx.x;
    const int n    = blockIdx.y;
    const int tid  = threadIdx.x;
    const int wq   = tid & 31;      // 32 groups of 2 px along the row
    const int cgrp = tid >> 5;      // 32 groups of 16 channels
    const int wb   = wq * 2;
    const int c0   = cgrp * 16;
    const int wave = tid >> 6;
    const int lane = tid & 63;

    __shared__ short xbuf[64 * XROW];   // 66560 B bf16 x1
    __shared__ float redS [16 * 64];    // [wave][px] partial sums
    __shared__ float redS2[16 * 64];
    __shared__ float mu_s[64];
    __shared__ float rs_s[64];

    // ---------- depthwise 3x3 conv + bias ----------
    float xv[2][16];                    // fully-unrolled static accesses only
    float sw0 = 0.f, sw1 = 0.f, sq0 = 0.f, sq1 = 0.f;

    const float* inbase = in_first + (size_t)(n * CC + c0) * HH * WW;

    #pragma unroll
    for (int i = 0; i < 16; ++i) {
        const int c = c0 + i;
        float w9[9];
        #pragma unroll
        for (int k = 0; k < 9; ++k) w9[k] = dw_w[c * 9 + k];
        const float b = dw_b[c];
        float a0 = b, a1 = b;
        #pragma unroll
        for (int r = 0; r < 3; ++r) {
            const int y = h + r - 1;
            if (y < 0 || y >= HH) continue;
            const float2 m = *(const float2*)(inbase + ((size_t)i * HH + y) * WW + wb);
            float left  = __shfl_up(m.y, 1);    // lane-1 is same-cgrp (wq-1); wq==0 masked
            float right = __shfl_down(m.x, 1);  // lane+1 is same-cgrp (wq+1); wq==31 masked
            if (wq == 0)  left  = 0.0f;
            if (wq == 31) right = 0.0f;
            const float k0 = w9[r * 3 + 0], k1 = w9[r * 3 + 1], k2 = w9[r * 3 + 2];
            a0 += k0 * left + k1 * m.x + k2 * m.y;
            a1 += k0 * m.x  + k1 * m.y + k2 * right;
        }
        xv[0][i] = a0; xv[1][i] = a1;
        sw0 += a0; sq0 += a0 * a0;
        sw1 += a1; sq1 += a1 * a1;
    }

    // ---------- LayerNorm stats: shfl over the wave's 2 cgrps, LDS over waves ----------
    sw0 += __shfl_xor(sw0, 32); sq0 += __shfl_xor(sq0, 32);
    sw1 += __shfl_xor(sw1, 32); sq1 += __shfl_xor(sq1, 32);
    if (lane < 32) {
        redS [wave * 64 + wb + 0] = sw0;  redS2[wave * 64 + wb + 0] = sq0;
        redS [wave * 64 + wb + 1] = sw1;  redS2[wave * 64 + wb + 1] = sq1;
    }
    __syncthreads();
    if (tid < 64) {
        float s = 0.f, s2 = 0.f;
        #pragma unroll
        for (int k = 0; k < 16; ++k) {
            s  += redS [k * 64 + tid];
            s2 += redS2[k * 64 + tid];
        }
        const float mu  = s * (1.0f / 512.0f);
        const float var = s2 * (1.0f / 512.0f) - mu * mu;
        mu_s[tid] = mu;
        rs_s[tid] = rsqrtf(var + 1e-6f);
    }
    __syncthreads();

    // ---------- LN affine + exact GELU + bf16 pack -> LDS x1 ----------
    {
        const float mu0 = mu_s[wb + 0], rs0 = rs_s[wb + 0];
        const float mu1 = mu_s[wb + 1], rs1 = rs_s[wb + 1];
        unsigned pk0[8], pk1[8];
        #pragma unroll
        for (int t = 0; t < 8; ++t) {
            const int c = c0 + 2 * t;
            const float lgA = ln_g[c],     lbA = ln_b[c];
            const float lgB = ln_g[c + 1], lbB = ln_b[c + 1];
            const float v0a = (xv[0][2 * t]     - mu0) * rs0 * lgA + lbA;
            const float v0b = (xv[0][2 * t + 1] - mu0) * rs0 * lgB + lbB;
            const float v1a = (xv[1][2 * t]     - mu1) * rs1 * lgA + lbA;
            const float v1b = (xv[1][2 * t + 1] - mu1) * rs1 * lgB + lbB;
            pk0[t] = pack_bf2(gelu_exact(v0a), gelu_exact(v0b));
            pk1[t] = pack_bf2(gelu_exact(v1a), gelu_exact(v1b));
        }
        short* p0 = xbuf + (wb + 0) * XROW + c0;
        short* p1 = xbuf + (wb + 1) * XROW + c0;
        *(uint4*)(p0)     = make_uint4(pk0[0], pk0[1], pk0[2], pk0[3]);
        *(uint4*)(p0 + 8) = make_uint4(pk0[4], pk0[5], pk0[6], pk0[7]);
        *(uint4*)(p1)     = make_uint4(pk1[0], pk1[1], pk1[2], pk1[3]);
        *(uint4*)(p1 + 8) = make_uint4(pk1[4], pk1[5], pk1[6], pk1[7]);
    }
    __syncthreads();

    // ---------- offset GEMM: waves 0-7, each one 16(px) x 16(o) tile, K=512 ----------
    // A-frag from LDS x1 (stride XROW -> (ml+quad) mod 8 spreads all 8 16B-groups,
    // conflict-free). B-frag off_w fp32 -> bf16 inline (L2-hot, 64 KiB total).
    // C/D layout (verified m89/m91): col = lane&15, row = (lane>>4)*4 + reg.
    if (wave < 8) {
        const int ml   = lane & 15;
        const int quad = lane >> 4;
        const int pxT  = wave >> 1;
        const int oT   = wave & 1;

        const short* arow = xbuf + (pxT * 16 + ml) * XROW + quad * 8;
        const float* brow = off_w + (size_t)(oT * 16 + ml) * CC + quad * 8;

        f32x4 acc = {0.f, 0.f, 0.f, 0.f};
        for (int k = 0; k < CC; k += 32) {
            const bf16x8 af = *(const bf16x8*)(arow + k);
            const float4 p = *(const float4*)(brow + k);
            const float4 q = *(const float4*)(brow + k + 4);
            union { bf16x8 v; unsigned u[4]; } bb;
            bb.u[0] = pack_bf2(p.x, p.y); bb.u[1] = pack_bf2(p.z, p.w);
            bb.u[2] = pack_bf2(q.x, q.y); bb.u[3] = pack_bf2(q.z, q.w);
            acc = __builtin_amdgcn_mfma_f32_16x16x32_bf16(af, bb.v, acc, 0, 0, 0);
        }

        const int   o   = oT * 16 + ml;
        const float ob  = off_b[o];
        const int   par = o & 1;            // even o -> x-offset, odd -> y-offset
        const int   g   = o >> 1;
        #pragma unroll
        for (int r = 0; r < 4; ++r) {
            const int w = pxT * 16 + quad * 4 + r;
            const float base = par ? (float)h : (float)w;
            coords[(size_t)par * NGHW + (((size_t)n * GG + g) * HH + h) * WW + w]
                = base + acc[r] + ob;
        }
    }
}

// ============================================================================
// Kernel 2: bilinear gather + LDS transpose + coalesced NCHW store (unchanged).
// grid (HH, NB, GG), block 256.
// ============================================================================
__global__ __launch_bounds__(256)
void sample_kernel(const float* __restrict__ in_last,
                   const float* __restrict__ coord_ws,
                   float* __restrict__ out)
{
    const int h   = blockIdx.x;
    const int n   = blockIdx.y;
    const int g   = blockIdx.z;
    const int tid = threadIdx.x;

    __shared__ float pxs[64];
    __shared__ float pys[64];
    __shared__ float smem[64 * 33];

    if (tid < 128) {
        const int w = tid & 63;
        const size_t cidx = (((size_t)n * GG + g) * HH + h) * WW + w;
        if (tid < 64) pxs[w] = coord_ws[cidx];
        else          pys[w] = coord_ws[cidx + NGHW];
    }
    __syncthreads();

    const int c4    = tid & 7;
    const int wslot = tid >> 3;
    const float* base = in_last + (size_t)n * HH * WW * CC + g * GCH + c4 * 4;

    #pragma unroll
    for (int pass = 0; pass < 2; ++pass) {
        const int w = wslot + pass * 32;
        const float px = pxs[w];
        const float py = pys[w];
        const float x0f = floorf(px), y0f = floorf(py);
        const float fx = px - x0f, fy = py - y0f;
        const int x0 = (int)x0f, y0 = (int)y0f;

        float4 acc = make_float4(0.f, 0.f, 0.f, 0.f);
        #pragma unroll
        for (int t = 0; t < 4; ++t) {
            const int xi = x0 + (t & 1);
            const int yi = y0 + (t >> 1);
            const float wt = ((t & 1) ? fx : 1.0f - fx) * ((t >> 1) ? fy : 1.0f - fy);
            if (xi >= 0 && xi < WW && yi >= 0 && yi < HH) {
                const float4 v = *(const float4*)(base + ((size_t)yi * WW + xi) * CC);
                acc.x += wt * v.x;
                acc.y += wt * v.y;
                acc.z += wt * v.z;
                acc.w += wt * v.w;
            }
        }
        float* sp = smem + w * 33 + c4 * 4;
        sp[0] = acc.x; sp[1] = acc.y; sp[2] = acc.z; sp[3] = acc.w;
    }
    __syncthreads();

    const int w  = tid & 63;
    const int cb = tid >> 6;
    float* op = out + (((size_t)n * CC + g * GCH) * HH + h) * WW + w;
    #pragma unroll
    for (int pass = 0; pass < 8; ++pass) {
        const int c = pass * 4 + cb;
        op[(size_t)c * (HH * WW)] = smem[w * 33 + c];
    }
}

extern "C" void kernel_launch(void* const* d_in, const int* in_sizes, int n_in,
                              void* d_out, int out_size, void* d_ws, size_t ws_size,
                              hipStream_t stream) {
    const float* in_first = (const float*)d_in[0];
    const float* in_last  = (const float*)d_in[1];
    const float* dw_w     = (const float*)d_in[2];
    const float* dw_b     = (const float*)d_in[3];
    const float* ln_g     = (const float*)d_in[4];
    const float* ln_b     = (const float*)d_in[5];
    const float* off_w    = (const float*)d_in[6];
    const float* off_b    = (const float*)d_in[7];
    float* out = (float*)d_out;

    float* coord_ws = (float*)d_ws;     // 4 MiB

    dim3 gridA(HH, NB);
    fused_conv_ln_gelu_off_kernel<<<gridA, 1024, 0, stream>>>(
        in_first, dw_w, dw_b, ln_g, ln_b, off_w, off_b, coord_ws);

    dim3 gridB(HH, NB, GG);
    sample_kernel<<<gridB, 256, 0, stream>>>(in_last, coord_ws, out);
}

// Round 2
// 247.251 us; speedup vs baseline: 1.1968x; 1.1436x over previous
//
#include <hip/hip_runtime.h>
#include <hip/hip_bf16.h>
#include <math.h>

#define NB 8
#define CC 512
#define HH 64
#define WW 64
#define GG 16
#define GCH 32
#define OO 32                      // 2*G offset rows
#define NGHW (NB * GG * HH * WW)   // 524288 elements per coord buffer
#define NPX  (NB * HH * WW)        // 32768 pixels
#define XROW 520                   // LDS x1 row stride in bf16 (1040 B -> MFMA reads spread banks)

// ws layout: [0, 4 MiB) px/py coords. (x1 never touches HBM.)

__device__ __forceinline__ float gelu_exact(float x) {
    return 0.5f * x * (1.0f + erff(x * 0.70710678118654752f));
}

__device__ __forceinline__ unsigned pack_bf2(float a, float b) {
    __hip_bfloat162 t = __float22bfloat162_rn(make_float2(a, b));
    return *(unsigned*)&t;
}

typedef __attribute__((ext_vector_type(8))) short bf16x8;
typedef __attribute__((ext_vector_type(4))) float f32x4;

// ============================================================================
// Fused kernel: dwconv3x3 + LayerNorm + GELU + offset-GEMM -> coords.
// grid (HH, NB), block 1024; conv thread = 4 w x 8 ch (float4 row loads +
// shfl halo). Round-1 lesson: occupancy was not the limiter, bytes-in-flight
// per wave is -> keep float4 load width (round-0) AND 2 blocks/CU (round-1).
// __launch_bounds__(1024,8) caps VGPR at 64 so both blocks stay resident.
// redS/redS2 alias the xbuf LDS (dead until after the stats phase) to keep
// LDS at ~67 KB < 80 KB. The 4px write mapping makes xbuf stores perfectly
// bank-balanced (16 wq x 4 cgrp -> all 8 bank groups, 8 lanes each).
// ============================================================================
__global__ __launch_bounds__(1024, 8)
void fused_conv_ln_gelu_off_kernel(const float* __restrict__ in_first,
                                   const float* __restrict__ dw_w,
                                   const float* __restrict__ dw_b,
                                   const float* __restrict__ ln_g,
                                   const float* __restrict__ ln_b,
                                   const float* __restrict__ off_w,
                                   const float* __restrict__ off_b,
                                   float* __restrict__ coords)
{
    const int h    = blockIdx.x;
    const int n    = blockIdx.y;
    const int tid  = threadIdx.x;
    const int wq   = tid & 15;      // 16 groups of 4 px along the row
    const int cgrp = tid >> 4;      // 64 groups of 8 channels
    const int wb   = wq * 4;
    const int c0   = cgrp * 8;
    const int wave = tid >> 6;
    const int lane = tid & 63;

    __shared__ short xbuf[64 * XROW];   // 66560 B bf16 x1 (aliased by redS below)
    __shared__ float mu_s[64];
    __shared__ float rs_s[64];
    float* redS  = (float*)xbuf;        // [16][64] partial sums  (8 KB, dead before xbuf written)
    float* redS2 = (float*)xbuf + 1024; // [16][64]

    // ---------- depthwise 3x3 conv + bias ----------
    float xv[4][8];                     // fully-unrolled static accesses only
    float sw[4] = {0.f, 0.f, 0.f, 0.f};
    float sq[4] = {0.f, 0.f, 0.f, 0.f};

    const float* inbase = in_first + ((size_t)n * CC + c0) * HH * WW;

    #pragma unroll
    for (int i = 0; i < 8; ++i) {
        const int c = c0 + i;
        float w9[9];
        #pragma unroll
        for (int k = 0; k < 9; ++k) w9[k] = dw_w[c * 9 + k];
        const float b = dw_b[c];
        float a0 = b, a1 = b, a2 = b, a3 = b;
        #pragma unroll
        for (int r = 0; r < 3; ++r) {
            const int y = h + r - 1;
            if (y < 0 || y >= HH) continue;           // uniform across block
            const float4 m = *(const float4*)(inbase + ((size_t)i * HH + y) * WW + wb);
            float left  = __shfl_up(m.w, 1);
            float right = __shfl_down(m.x, 1);
            if (wq == 0)  left  = 0.0f;
            if (wq == 15) right = 0.0f;
            const float k0 = w9[r * 3 + 0], k1 = w9[r * 3 + 1], k2 = w9[r * 3 + 2];
            a0 += k0 * left + k1 * m.x + k2 * m.y;
            a1 += k0 * m.x  + k1 * m.y + k2 * m.z;
            a2 += k0 * m.y  + k1 * m.z + k2 * m.w;
            a3 += k0 * m.z  + k1 * m.w + k2 * right;
        }
        xv[0][i] = a0; xv[1][i] = a1; xv[2][i] = a2; xv[3][i] = a3;
        sw[0] += a0; sq[0] += a0 * a0;
        sw[1] += a1; sq[1] += a1 * a1;
        sw[2] += a2; sq[2] += a2 * a2;
        sw[3] += a3; sq[3] += a3 * a3;
    }

    // ---------- LayerNorm stats: shfl over the wave's 4 cgrps, LDS over waves ----------
    #pragma unroll
    for (int j = 0; j < 4; ++j) {
        sw[j] += __shfl_xor(sw[j], 16); sw[j] += __shfl_xor(sw[j], 32);
        sq[j] += __shfl_xor(sq[j], 16); sq[j] += __shfl_xor(sq[j], 32);
    }
    if (lane < 16) {
        #pragma unroll
        for (int j = 0; j < 4; ++j) {
            redS [wave * 64 + wb + j] = sw[j];
            redS2[wave * 64 + wb + j] = sq[j];
        }
    }
    __syncthreads();
    if (tid < 64) {
        float s = 0.f, s2 = 0.f;
        #pragma unroll
        for (int k = 0; k < 16; ++k) {
            s  += redS [k * 64 + tid];
            s2 += redS2[k * 64 + tid];
        }
        const float mu  = s * (1.0f / 512.0f);
        const float var = s2 * (1.0f / 512.0f) - mu * mu;
        mu_s[tid] = mu;
        rs_s[tid] = rsqrtf(var + 1e-6f);
    }
    __syncthreads();   // redS reads done; xbuf (aliasing) may now be written

    // ---------- LN affine + exact GELU + bf16 pack -> LDS x1 ----------
    {
        float mu_[4], rs_[4];
        #pragma unroll
        for (int j = 0; j < 4; ++j) { mu_[j] = mu_s[wb + j]; rs_[j] = rs_s[wb + j]; }
        unsigned pk[4][4];
        #pragma unroll
        for (int t = 0; t < 4; ++t) {           // channel pairs
            const int c = c0 + 2 * t;
            const float lgA = ln_g[c],     lbA = ln_b[c];
            const float lgB = ln_g[c + 1], lbB = ln_b[c + 1];
            #pragma unroll
            for (int j = 0; j < 4; ++j) {
                const float va = (xv[j][2 * t]     - mu_[j]) * rs_[j] * lgA + lbA;
                const float vb = (xv[j][2 * t + 1] - mu_[j]) * rs_[j] * lgB + lbB;
                pk[j][t] = pack_bf2(gelu_exact(va), gelu_exact(vb));
            }
        }
        #pragma unroll
        for (int j = 0; j < 4; ++j) {
            *(uint4*)(xbuf + (size_t)(wb + j) * XROW + c0)
                = make_uint4(pk[j][0], pk[j][1], pk[j][2], pk[j][3]);
        }
    }
    __syncthreads();

    // ---------- offset GEMM: waves 0-7, each one 16(px) x 16(o) tile, K=512 ----------
    // C/D layout (verified m89/m91): col = lane&15, row = (lane>>4)*4 + reg.
    if (wave < 8) {
        const int ml   = lane & 15;
        const int quad = lane >> 4;
        const int pxT  = wave >> 1;
        const int oT   = wave & 1;

        const short* arow = xbuf + (size_t)(pxT * 16 + ml) * XROW + quad * 8;
        const float* brow = off_w + (size_t)(oT * 16 + ml) * CC + quad * 8;

        f32x4 acc = {0.f, 0.f, 0.f, 0.f};
        for (int k = 0; k < CC; k += 32) {
            const bf16x8 af = *(const bf16x8*)(arow + k);
            const float4 p = *(const float4*)(brow + k);
            const float4 q = *(const float4*)(brow + k + 4);
            union { bf16x8 v; unsigned u[4]; } bb;
            bb.u[0] = pack_bf2(p.x, p.y); bb.u[1] = pack_bf2(p.z, p.w);
            bb.u[2] = pack_bf2(q.x, q.y); bb.u[3] = pack_bf2(q.z, q.w);
            acc = __builtin_amdgcn_mfma_f32_16x16x32_bf16(af, bb.v, acc, 0, 0, 0);
        }

        const int   o   = oT * 16 + ml;
        const float ob  = off_b[o];
        const int   par = o & 1;            // even o -> x-offset, odd -> y-offset
        const int   g   = o >> 1;
        #pragma unroll
        for (int r = 0; r < 4; ++r) {
            const int w = pxT * 16 + quad * 4 + r;
            const float base = par ? (float)h : (float)w;
            coords[(size_t)par * NGHW + (((size_t)n * GG + g) * HH + h) * WW + w]
                = base + acc[r] + ob;
        }
    }
}

// ============================================================================
// Kernel 2: bilinear gather. 1D grid 8192 with XCD swizzle (blocks sharing
// (n,g) and adjacent h land on the same XCD -> row-overlap hits its L2).
// All 8 tap loads issued upfront (clamped address + zero weight instead of
// branches -> no divergence, 8 loads in flight per thread). float4 stores.
// ============================================================================
__global__ __launch_bounds__(256)
void sample_kernel(const float* __restrict__ in_last,
                   const float* __restrict__ coord_ws,
                   float* __restrict__ out)
{
    // bijective XCD swizzle: 8192 % 8 == 0; nb ordering is (g, n, h) with h fastest
    const int bid = blockIdx.x;
    const int nb  = (bid & 7) * 1024 + (bid >> 3);
    const int h   = nb & 63;
    const int n   = (nb >> 6) & 7;
    const int g   = nb >> 9;
    const int tid = threadIdx.x;

    __shared__ float pxs[64];
    __shared__ float pys[64];
    __shared__ float smem[64 * 33];

    if (tid < 128) {
        const int w = tid & 63;
        const size_t cidx = (((size_t)n * GG + g) * HH + h) * WW + w;
        if (tid < 64) pxs[w] = coord_ws[cidx];
        else          pys[w] = coord_ws[cidx + NGHW];
    }
    __syncthreads();

    const int c4    = tid & 7;      // 8 groups of 4 channels
    const int wslot = tid >> 3;     // 32 px slots (x2 passes)
    const float* base = in_last + (size_t)n * HH * WW * CC + g * GCH + c4 * 4;

    int   off[8];
    float wt [8];
    #pragma unroll
    for (int p = 0; p < 2; ++p) {
        const int w = wslot + p * 32;
        const float px = pxs[w];
        const float py = pys[w];
        const float x0f = floorf(px), y0f = floorf(py);
        const float fx = px - x0f, fy = py - y0f;
        const int x0 = (int)x0f, y0 = (int)y0f;
        #pragma unroll
        for (int t = 0; t < 4; ++t) {
            const int xi = x0 + (t & 1);
            const int yi = y0 + (t >> 1);
            const int xc = min(max(xi, 0), WW - 1);
            const int yc = min(max(yi, 0), HH - 1);
            const float valid = (xi >= 0 && xi < WW && yi >= 0 && yi < HH) ? 1.0f : 0.0f;
            wt [p * 4 + t] = ((t & 1) ? fx : 1.0f - fx) * ((t >> 1) ? fy : 1.0f - fy) * valid;
            off[p * 4 + t] = (yc * WW + xc) * CC;
        }
    }
    // all 8 independent loads in flight before any consume
    float4 v[8];
    #pragma unroll
    for (int i = 0; i < 8; ++i) v[i] = *(const float4*)(base + off[i]);

    float4 a0 = make_float4(0.f, 0.f, 0.f, 0.f);
    float4 a1 = make_float4(0.f, 0.f, 0.f, 0.f);
    #pragma unroll
    for (int t = 0; t < 4; ++t) {
        a0.x += wt[t] * v[t].x;     a0.y += wt[t] * v[t].y;
        a0.z += wt[t] * v[t].z;     a0.w += wt[t] * v[t].w;
        a1.x += wt[4 + t] * v[4 + t].x; a1.y += wt[4 + t] * v[4 + t].y;
        a1.z += wt[4 + t] * v[4 + t].z; a1.w += wt[4 + t] * v[4 + t].w;
    }
    {
        float* sp0 = smem + wslot * 33 + c4 * 4;
        float* sp1 = smem + (wslot + 32) * 33 + c4 * 4;
        sp0[0] = a0.x; sp0[1] = a0.y; sp0[2] = a0.z; sp0[3] = a0.w;
        sp1[0] = a1.x; sp1[1] = a1.y; sp1[2] = a1.z; sp1[3] = a1.w;
    }
    __syncthreads();

    // transpose out of LDS, float4 along w
    const int c  = tid >> 4;            // 0..15 (x2 passes)
    const int w4 = (tid & 15) * 4;
    #pragma unroll
    for (int p = 0; p < 2; ++p) {
        const int cc = c + p * 16;
        float4 o;
        o.x = smem[(w4 + 0) * 33 + cc];
        o.y = smem[(w4 + 1) * 33 + cc];
        o.z = smem[(w4 + 2) * 33 + cc];
        o.w = smem[(w4 + 3) * 33 + cc];
        *(float4*)(out + (((size_t)n * CC + g * GCH + cc) * HH + h) * WW + w4) = o;
    }
}

extern "C" void kernel_launch(void* const* d_in, const int* in_sizes, int n_in,
                              void* d_out, int out_size, void* d_ws, size_t ws_size,
                              hipStream_t stream) {
    const float* in_first = (const float*)d_in[0];
    const float* in_last  = (const float*)d_in[1];
    const float* dw_w     = (const float*)d_in[2];
    const float* dw_b     = (const float*)d_in[3];
    const float* ln_g     = (const float*)d_in[4];
    const float* ln_b     = (const float*)d_in[5];
    const float* off_w    = (const float*)d_in[6];
    const float* off_b    = (const float*)d_in[7];
    float* out = (float*)d_out;

    float* coord_ws = (float*)d_ws;     // 4 MiB

    dim3 gridA(HH, NB);
    fused_conv_ln_gelu_off_kernel<<<gridA, 1024, 0, stream>>>(
        in_first, dw_w, dw_b, ln_g, ln_b, off_w, off_b, coord_ws);

    sample_kernel<<<HH * NB * GG, 256, 0, stream>>>(in_last, coord_ws, out);
}